// Round 8
// baseline (880.844 us; speedup 1.0000x reference)
//
#include <hip/hip_runtime.h>
#include <hip/hip_bf16.h>

#define T_SEQ 1024
#define BATCH 512
#define INPUT 64
#define HID   128

typedef __attribute__((ext_vector_type(8))) short bf16x8;
typedef __attribute__((ext_vector_type(4))) short s16x4;
typedef __attribute__((ext_vector_type(4))) float f32x4;
typedef __attribute__((ext_vector_type(2))) unsigned int u32x2;

#define MFMA __builtin_amdgcn_mfma_f32_16x16x32_bf16

__device__ __forceinline__ short f2bf(float f) {
    union { float f; unsigned u; } v; v.f = f;
    unsigned r = (v.u + 0x7FFFu + ((v.u >> 16) & 1u)) >> 16;
    return (short)r;
}

// packed RNE f32x2 -> bf16x2 (single VOP3)
__device__ __forceinline__ unsigned cvtpk_bf16(float lo, float hi) {
    unsigned r;
    asm("v_cvt_pk_bf16_f32 %0, %1, %2" : "=v"(r) : "v"(lo), "v"(hi));
    return r;
}

// 8 f32 -> bf16x8 frag via 4 cvt_pk (R5's 64-VALU manual chain was the regression)
__device__ __forceinline__ bf16x8 pack_bf16x8(f32x4 a, f32x4 b) {
    union { unsigned u[4]; bf16x8 v; } r;
    r.u[0] = cvtpk_bf16(a[0], a[1]);
    r.u[1] = cvtpk_bf16(a[2], a[3]);
    r.u[2] = cvtpk_bf16(b[0], b[1]);
    r.u[3] = cvtpk_bf16(b[2], b[3]);
    return r.v;
}

// tanh(x) = 1 - 2/(exp(2x)+1); inf-safe
__device__ __forceinline__ float fast_tanh(float s) {
    float e = __expf(2.0f * s);
    return 1.0f - 2.0f * __builtin_amdgcn_rcpf(e + 1.0f);
}

__device__ __forceinline__ float hsig(float v) {
    return __builtin_amdgcn_fmed3f(v * 0.16666666666666666f + 0.5f, 0.0f, 1.0f);
}

// Barrier draining ONLY lgkmcnt (LDS). Global x-prefetch loads stay in flight.
__device__ __forceinline__ void wg_barrier_lds() {
    asm volatile("s_waitcnt lgkmcnt(0)" ::: "memory");
    __builtin_amdgcn_s_barrier();
    asm volatile("" ::: "memory");
}

// ---------------- Stage 1: recurrence (R2 structure) + fused W_map cvt ----------------
// Grid 64x512: blocks 0-31 run the recurrence (16 batches each); blocks 32-63
// convert W_map f32->bf16 (independent work, runs on idle CUs during the rnn).
// Launch-count reduction: R7 accounting shows ~52us wall per extra kernel+gap.
// x is read as f32 DIRECTLY (no cvt_x kernel): raw f32x4 loads issued in the
// CRITICAL interval (2-3 barrier intervals of flight), converted in the shadow
// via 8 v_cvt_pk_bf16_f32 (R5's regression was a 64-VALU manual convert chain).
// Group A (waves 0-3) owns even t, group B (waves 4-7) odd t; 1 barrier/step.
__global__ __launch_bounds__(512, 2) void rnn_kernel(
    const float* __restrict__ xf_,
    const float* __restrict__ W_ih, const float* __restrict__ b_ih,
    const float* __restrict__ W_hh, const float* __restrict__ b_hh,
    const float* __restrict__ W_gate, const float* __restrict__ b_gate,
    float* __restrict__ agg_out,
    const float* __restrict__ W_map, short* __restrict__ wm_bf)
{
    if (blockIdx.x >= 32) {
        // ---- W_map f32 -> bf16, grid-stride over 32 blocks ----
        const int n4 = 16384 * HID / 4;
        for (int i = (blockIdx.x - 32) * 512 + threadIdx.x; i < n4; i += 32 * 512) {
            f32x4 v = ((const f32x4*)W_map)[i];
            s16x4 o;
            #pragma unroll
            for (int j = 0; j < 4; ++j) o[j] = f2bf(v[j]);
            ((s16x4*)wm_bf)[i] = o;
        }
        return;
    }

    __shared__ __align__(16) short sh[2][16][136];

    const int tid  = threadIdx.x;
    const int wave = tid >> 6, lane = tid & 63;
    const int q = lane >> 4, l15 = lane & 15;
    const int b0 = blockIdx.x * 16;
    const int group = wave >> 2;          // 0: even steps, 1: odd steps
    const int gw = wave & 3;              // hidden rows [32*gw, 32*gw+32)
    const int R0 = 32 * gw, R1 = R0 + 16;

    // ---- one-time: weight A-frags (lane: W[row = Rt + l15][k = 32f + q*8 + j]) ----
    bf16x8 wih[2][2], whh[2][4], wgf[2][4];
    #pragma unroll
    for (int tile = 0; tile < 2; ++tile) {
        const int row = (tile ? R1 : R0) + l15;
        #pragma unroll
        for (int f = 0; f < 2; ++f) {
            const float* p = W_ih + row * INPUT + f * 32 + q * 8;
            bf16x8 v;
            #pragma unroll
            for (int j = 0; j < 8; ++j) v[j] = f2bf(p[j]);
            wih[tile][f] = v;
        }
        #pragma unroll
        for (int f = 0; f < 4; ++f) {
            const float* p = W_hh + row * HID + f * 32 + q * 8;
            bf16x8 v;
            #pragma unroll
            for (int j = 0; j < 8; ++j) v[j] = f2bf(p[j]);
            whh[tile][f] = v;
        }
        #pragma unroll
        for (int f = 0; f < 4; ++f) {
            const float* p = W_gate + row * HID + f * 32 + q * 8;
            bf16x8 v;
            #pragma unroll
            for (int j = 0; j < 8; ++j) v[j] = f2bf(p[j]);
            wgf[tile][f] = v;
        }
    }

    // ---- biases in C^T layout: row = Rt + q*4 + r ----
    f32x4 bias1[2], biasg[2], zero4;
    #pragma unroll
    for (int tile = 0; tile < 2; ++tile) {
        const int rbase = (tile ? R1 : R0) + q * 4;
        #pragma unroll
        for (int r = 0; r < 4; ++r) {
            bias1[tile][r] = b_ih[rbase + r] + b_hh[rbase + r];
            biasg[tile][r] = b_gate[rbase + r];
        }
    }
    #pragma unroll
    for (int r = 0; r < 4; ++r) zero4[r] = 0.0f;

    f32x4 agg0 = zero4, agg1 = zero4;
    f32x4 hpA = zero4, hpB = zero4;       // own h(s) values (f32, C^T layout)
    f32x4 accx0, accx1;                   // x-part for next own critical step
    // raw f32 x double-buffer: loaded in critical(t) for x(t+4), consumed in shadow
    f32x4 P0, P1, P2, P3, Q0, Q1, Q2, Q3;

    const float* xf_lane = xf_ + ((long)(b0 + l15) * T_SEQ) * INPUT + q * 8;

    auto load_raw = [&](int tt, f32x4& r0, f32x4& r1, f32x4& r2, f32x4& r3) {
        if (tt > T_SEQ - 1) tt = T_SEQ - 1;
        const float* p = xf_lane + (long)tt * INPUT;
        r0 = *(const f32x4*)p;        r1 = *(const f32x4*)(p + 4);
        r2 = *(const f32x4*)(p + 32); r3 = *(const f32x4*)(p + 36);
    };

    // critical t: h(t) = tanh(W_hh h(t-1) + accx(t)); write sh[t&1]; issue x(t+4) loads
    auto critical = [&](int t, f32x4& r0, f32x4& r1, f32x4& r2, f32x4& r3) {
        const int rb = (t & 1) ^ 1, wb = t & 1;
        bf16x8 hf0 = *(const bf16x8*)&sh[rb][l15][q * 8];
        bf16x8 hf1 = *(const bf16x8*)&sh[rb][l15][32 + q * 8];
        bf16x8 hf2 = *(const bf16x8*)&sh[rb][l15][64 + q * 8];
        bf16x8 hf3 = *(const bf16x8*)&sh[rb][l15][96 + q * 8];
        f32x4 a0 = MFMA(whh[0][0], hf0, accx0, 0, 0, 0);
        f32x4 c0 = MFMA(whh[0][2], hf2, zero4, 0, 0, 0);
        f32x4 a1 = MFMA(whh[1][0], hf0, accx1, 0, 0, 0);
        f32x4 c1 = MFMA(whh[1][2], hf2, zero4, 0, 0, 0);
        a0 = MFMA(whh[0][1], hf1, a0, 0, 0, 0);
        c0 = MFMA(whh[0][3], hf3, c0, 0, 0, 0);
        a1 = MFMA(whh[1][1], hf1, a1, 0, 0, 0);
        c1 = MFMA(whh[1][3], hf3, c1, 0, 0, 0);
        // fire-and-forget raw x loads (consumed 2-3 intervals later in shadow)
        load_raw(t + 4, r0, r1, r2, r3);
        hpA[0] = fast_tanh(a0[0] + c0[0]);
        hpA[1] = fast_tanh(a0[1] + c0[1]);
        hpA[2] = fast_tanh(a0[2] + c0[2]);
        hpA[3] = fast_tanh(a0[3] + c0[3]);
        hpB[0] = fast_tanh(a1[0] + c1[0]);
        hpB[1] = fast_tanh(a1[1] + c1[1]);
        hpB[2] = fast_tanh(a1[2] + c1[2]);
        hpB[3] = fast_tanh(a1[3] + c1[3]);
        u32x2 p0, p1;
        p0[0] = cvtpk_bf16(hpA[0], hpA[1]); p0[1] = cvtpk_bf16(hpA[2], hpA[3]);
        p1[0] = cvtpk_bf16(hpB[0], hpB[1]); p1[1] = cvtpk_bf16(hpB[2], hpB[3]);
        *(u32x2*)&sh[wb][l15][R0 + q * 4] = p0;
        *(u32x2*)&sh[wb][l15][R1 + q * 4] = p1;
    };

    // shadow t: gate(t-1) + agg; accx(t+1) from raw regs via cvt_pk
    auto shadow = [&](int t, f32x4& r0, f32x4& r1, f32x4& r2, f32x4& r3) {
        const int rb = (t & 1) ^ 1;
        bf16x8 gf0 = *(const bf16x8*)&sh[rb][l15][q * 8];
        bf16x8 gf1 = *(const bf16x8*)&sh[rb][l15][32 + q * 8];
        bf16x8 gf2 = *(const bf16x8*)&sh[rb][l15][64 + q * 8];
        bf16x8 gf3 = *(const bf16x8*)&sh[rb][l15][96 + q * 8];
        // convert raw x(t+1) -> frags: 8 cvt_pk total
        bf16x8 fa = pack_bf16x8(r0, r1);
        bf16x8 fb = pack_bf16x8(r2, r3);
        accx0 = MFMA(wih[0][0], fa, bias1[0], 0, 0, 0);
        accx1 = MFMA(wih[1][0], fa, bias1[1], 0, 0, 0);
        accx0 = MFMA(wih[0][1], fb, accx0, 0, 0, 0);
        accx1 = MFMA(wih[1][1], fb, accx1, 0, 0, 0);
        f32x4 g0 = MFMA(wgf[0][0], gf0, biasg[0], 0, 0, 0);
        f32x4 e0 = MFMA(wgf[0][2], gf2, zero4, 0, 0, 0);
        f32x4 g1 = MFMA(wgf[1][0], gf0, biasg[1], 0, 0, 0);
        f32x4 e1 = MFMA(wgf[1][2], gf2, zero4, 0, 0, 0);
        g0 = MFMA(wgf[0][1], gf1, g0, 0, 0, 0);
        e0 = MFMA(wgf[0][3], gf3, e0, 0, 0, 0);
        g1 = MFMA(wgf[1][1], gf1, g1, 0, 0, 0);
        e1 = MFMA(wgf[1][3], gf3, e1, 0, 0, 0);
        #pragma unroll
        for (int r = 0; r < 4; ++r) {
            agg0[r] += hpA[r] * hsig(g0[r] + e0[r]);
            agg1[r] += hpB[r] * hsig(g1[r] + e1[r]);
        }
    };

    // ---- prologue ----
    {
        // accx(group) inline: load x(0) (A) / x(1) (B), convert, MFMA
        f32x4 a0, a1, a2, a3;
        load_raw(group, a0, a1, a2, a3);
        bf16x8 ta = pack_bf16x8(a0, a1);
        bf16x8 tb = pack_bf16x8(a2, a3);
        accx0 = MFMA(wih[0][0], ta, bias1[0], 0, 0, 0);
        accx1 = MFMA(wih[1][0], ta, bias1[1], 0, 0, 0);
        accx0 = MFMA(wih[0][1], tb, accx0, 0, 0, 0);
        accx1 = MFMA(wih[1][1], tb, accx1, 0, 0, 0);
        if (group == 0) {
            // h(0) = tanh(accx(0)); write buf[0]
            hpA[0] = fast_tanh(accx0[0]); hpA[1] = fast_tanh(accx0[1]);
            hpA[2] = fast_tanh(accx0[2]); hpA[3] = fast_tanh(accx0[3]);
            hpB[0] = fast_tanh(accx1[0]); hpB[1] = fast_tanh(accx1[1]);
            hpB[2] = fast_tanh(accx1[2]); hpB[3] = fast_tanh(accx1[3]);
            u32x2 p0, p1;
            p0[0] = cvtpk_bf16(hpA[0], hpA[1]); p0[1] = cvtpk_bf16(hpA[2], hpA[3]);
            p1[0] = cvtpk_bf16(hpB[0], hpB[1]); p1[1] = cvtpk_bf16(hpB[2], hpB[3]);
            *(u32x2*)&sh[0][l15][R0 + q * 4] = p0;
            *(u32x2*)&sh[0][l15][R1 + q * 4] = p1;
            // A: prefetch x(2)->P, x(4)->Q
            load_raw(2, P0, P1, P2, P3);
            load_raw(4, Q0, Q1, Q2, Q3);
        } else {
            // B: prefetch x(3)->P (Q filled by critical(1))
            load_raw(3, P0, P1, P2, P3);
        }
    }
    wg_barrier_lds();

    // ---- main loop ----
    // Buffer schedule (derived): A: shadow cons P,Q,P,Q...; critical(t) loads x(t+4)
    // into the buffer its (t+3)-shadow will consume. B symmetric.
    if (group == 0) {
        shadow(1, P0, P1, P2, P3);                 wg_barrier_lds();
        critical(2, P0, P1, P2, P3);               wg_barrier_lds();
        for (int i = 0; i < 255; ++i) {
            shadow(4 * i + 3, Q0, Q1, Q2, Q3);     wg_barrier_lds();
            critical(4 * i + 4, Q0, Q1, Q2, Q3);   wg_barrier_lds();
            shadow(4 * i + 5, P0, P1, P2, P3);     wg_barrier_lds();
            critical(4 * i + 6, P0, P1, P2, P3);   wg_barrier_lds();
        }
        shadow(1023, Q0, Q1, Q2, Q3);              wg_barrier_lds();
    } else {
        critical(1, Q0, Q1, Q2, Q3);               wg_barrier_lds();
        shadow(2, P0, P1, P2, P3);                 wg_barrier_lds();
        for (int i = 0; i < 255; ++i) {
            critical(4 * i + 3, P0, P1, P2, P3);   wg_barrier_lds();
            shadow(4 * i + 4, Q0, Q1, Q2, Q3);     wg_barrier_lds();
            critical(4 * i + 5, Q0, Q1, Q2, Q3);   wg_barrier_lds();
            shadow(4 * i + 6, P0, P1, P2, P3);     wg_barrier_lds();
        }
        critical(1023, P0, P1, P2, P3);            wg_barrier_lds();
    }

    // ---- epilogue ----
    // B owns h(1023) (in sh[1]): compute its last gate term.
    if (group == 1) {
        bf16x8 gf0 = *(const bf16x8*)&sh[1][l15][q * 8];
        bf16x8 gf1 = *(const bf16x8*)&sh[1][l15][32 + q * 8];
        bf16x8 gf2 = *(const bf16x8*)&sh[1][l15][64 + q * 8];
        bf16x8 gf3 = *(const bf16x8*)&sh[1][l15][96 + q * 8];
        f32x4 g0 = MFMA(wgf[0][0], gf0, biasg[0], 0, 0, 0);
        f32x4 e0 = MFMA(wgf[0][2], gf2, zero4, 0, 0, 0);
        f32x4 g1 = MFMA(wgf[1][0], gf0, biasg[1], 0, 0, 0);
        f32x4 e1 = MFMA(wgf[1][2], gf2, zero4, 0, 0, 0);
        g0 = MFMA(wgf[0][1], gf1, g0, 0, 0, 0);
        e0 = MFMA(wgf[0][3], gf3, e0, 0, 0, 0);
        g1 = MFMA(wgf[1][1], gf1, g1, 0, 0, 0);
        e1 = MFMA(wgf[1][3], gf3, e1, 0, 0, 0);
        #pragma unroll
        for (int r = 0; r < 4; ++r) {
            agg0[r] += hpA[r] * hsig(g0[r] + e0[r]);
            agg1[r] += hpB[r] * hsig(g1[r] + e1[r]);
        }
    }
    wg_barrier_lds();                      // B's gf reads done before A overwrites LDS

    float* aggf = (float*)&sh[0][0][0];    // reuse as float[16][128]
    if (group == 0) {
        *(f32x4*)&aggf[l15 * HID + R0 + q * 4] = agg0;
        *(f32x4*)&aggf[l15 * HID + R1 + q * 4] = agg1;
    }
    wg_barrier_lds();
    if (group == 1) {
        const float s = 1.0f / (float)T_SEQ;
        f32x4 t0 = *(const f32x4*)&aggf[l15 * HID + R0 + q * 4];
        f32x4 t1 = *(const f32x4*)&aggf[l15 * HID + R1 + q * 4];
        #pragma unroll
        for (int r = 0; r < 4; ++r) { t0[r] = (t0[r] + agg0[r]) * s; t1[r] = (t1[r] + agg1[r]) * s; }
        *(f32x4*)&agg_out[(long)(b0 + l15) * HID + R0 + q * 4] = t0;
        *(f32x4*)&agg_out[(long)(b0 + l15) * HID + R1 + q * 4] = t1;
    }
}

// ---------------- Stage 2: mapped = agg @ W_map^T + b_map, FUSED pool+gate ----------------
// Block (mb, nb): batches mb*16..+16, cols nb*128..+128. The block covers exactly
// one pool-window row -> 4x4 pooling is block-local. shfl over 4-lane w-groups,
// per-wave LDS partials over h, gate = hsig(sum/16), multiply before the store.
template<bool PRE>
__global__ __launch_bounds__(256) void map_kernel(
    const float* __restrict__ agg, const float* __restrict__ Wf,
    const short* __restrict__ Wb, const float* __restrict__ b_map,
    float* __restrict__ out)
{
    __shared__ float sh_pool[4][16][8];
    __shared__ float sh_gate[16][8];

    const int tid  = threadIdx.x;
    const int wave = tid >> 6, lane = tid & 63;
    const int q = lane >> 4, l15 = lane & 15;
    const int mb = blockIdx.x & 31;
    const int nb = blockIdx.x >> 5;
    const int b0 = mb * 16;
    const int n0 = nb * 128 + wave * 32;

    bf16x8 af[4];
    #pragma unroll
    for (int kb = 0; kb < 4; ++kb) {
        const float* p = agg + (b0 + l15) * HID + kb * 32 + q * 8;
        bf16x8 f;
        #pragma unroll
        for (int j = 0; j < 8; ++j) f[j] = f2bf(p[j]);
        af[kb] = f;
    }
    f32x4 cc[2];
    #pragma unroll
    for (int tn = 0; tn < 2; ++tn) {
        int nn = n0 + tn * 16 + l15;
        float bias = b_map[nn];
        f32x4 c;
        #pragma unroll
        for (int r = 0; r < 4; ++r) c[r] = bias;
        #pragma unroll
        for (int kb = 0; kb < 4; ++kb) {
            bf16x8 f;
            if (PRE) {
                f = *(const bf16x8*)(Wb + (long)nn * HID + kb * 32 + q * 8);
            } else {
                const float* p = Wf + (long)nn * HID + kb * 32 + q * 8;
                #pragma unroll
                for (int j = 0; j < 8; ++j) f[j] = f2bf(p[j]);
            }
            c = __builtin_amdgcn_mfma_f32_16x16x32_bf16(af[kb], f, c, 0, 0, 0);
        }
        cc[tn] = c;
        // pool partial: sum over 4-lane w-groups
        f32x4 t = c;
        #pragma unroll
        for (int r = 0; r < 4; ++r) {
            t[r] += __shfl_xor(t[r], 1);
            t[r] += __shfl_xor(t[r], 2);
        }
        if ((l15 & 3) == 0) {
            int pw = tn * 4 + (l15 >> 2);
            #pragma unroll
            for (int r = 0; r < 4; ++r) sh_pool[wave][q * 4 + r][pw] = t[r];
        }
    }
    __syncthreads();
    if (tid < 128) {
        int b = tid >> 3, pw = tid & 7;
        float s = sh_pool[0][b][pw] + sh_pool[1][b][pw] +
                  sh_pool[2][b][pw] + sh_pool[3][b][pw];
        sh_gate[b][pw] = hsig(s * (1.0f / 16.0f));
    }
    __syncthreads();
    #pragma unroll
    for (int tn = 0; tn < 2; ++tn) {
        int nn = n0 + tn * 16 + l15;
        int pw = tn * 4 + (l15 >> 2);
        #pragma unroll
        for (int r = 0; r < 4; ++r)
            out[(long)(b0 + q * 4 + r) * 16384 + nn] = cc[tn][r] * sh_gate[q * 4 + r][pw];
    }
}

extern "C" void kernel_launch(void* const* d_in, const int* in_sizes, int n_in,
                              void* d_out, int out_size, void* d_ws, size_t ws_size,
                              hipStream_t stream) {
    const float* x      = (const float*)d_in[0];
    const float* W_ih   = (const float*)d_in[1];
    const float* b_ih   = (const float*)d_in[2];
    const float* W_hh   = (const float*)d_in[3];
    const float* b_hh   = (const float*)d_in[4];
    const float* W_gate = (const float*)d_in[5];
    const float* b_gate = (const float*)d_in[6];
    const float* W_map  = (const float*)d_in[7];
    const float* b_map  = (const float*)d_in[8];
    float* out = (float*)d_out;

    const size_t wm_bytes  = (size_t)16384 * HID * 2;
    const size_t agg_bytes = (size_t)BATCH * HID * 4;
    const bool pre = ws_size >= wm_bytes + agg_bytes;

    if (pre) {
        short* wm_bf = (short*)d_ws;
        float* agg   = (float*)((char*)d_ws + wm_bytes);

        // blocks 0-31: recurrence; blocks 32-63: W_map f32->bf16 (concurrent)
        rnn_kernel<<<64, 512, 0, stream>>>(x, W_ih, b_ih, W_hh, b_hh,
                                           W_gate, b_gate, agg, W_map, wm_bf);
        map_kernel<true><<<4096, 256, 0, stream>>>(agg, W_map, wm_bf, b_map, out);
    } else {
        float* agg = (float*)d_ws;
        rnn_kernel<<<32, 512, 0, stream>>>(x, W_ih, b_ih, W_hh, b_hh,
                                           W_gate, b_gate, agg, nullptr, nullptr);
        map_kernel<false><<<4096, 256, 0, stream>>>(agg, W_map, nullptr, b_map, out);
    }
}

// Round 9
// 684.712 us; speedup vs baseline: 1.2864x; 1.2864x over previous
//
#include <hip/hip_runtime.h>
#include <hip/hip_bf16.h>

#define T_SEQ 1024
#define BATCH 512
#define INPUT 64
#define HID   128

typedef __attribute__((ext_vector_type(8))) short bf16x8;
typedef __attribute__((ext_vector_type(4))) short s16x4;
typedef __attribute__((ext_vector_type(4))) float f32x4;
typedef __attribute__((ext_vector_type(2))) unsigned int u32x2;

#define MFMA __builtin_amdgcn_mfma_f32_16x16x32_bf16

__device__ __forceinline__ short f2bf(float f) {
    union { float f; unsigned u; } v; v.f = f;
    unsigned r = (v.u + 0x7FFFu + ((v.u >> 16) & 1u)) >> 16;
    return (short)r;
}

// packed RNE f32x2 -> bf16x2
__device__ __forceinline__ unsigned cvtpk_bf16(float lo, float hi) {
    unsigned r;
    asm("v_cvt_pk_bf16_f32 %0, %1, %2" : "=v"(r) : "v"(lo), "v"(hi));
    return r;
}

// tanh(x) = 1 - 2/(exp(2x)+1); inf-safe
__device__ __forceinline__ float fast_tanh(float s) {
    float e = __expf(2.0f * s);
    return 1.0f - 2.0f * __builtin_amdgcn_rcpf(e + 1.0f);
}

__device__ __forceinline__ float hsig(float v) {
    return __builtin_amdgcn_fmed3f(v * 0.16666666666666666f + 0.5f, 0.0f, 1.0f);
}

// Barrier draining ONLY lgkmcnt (LDS). Global x-prefetch loads stay in flight.
__device__ __forceinline__ void wg_barrier_lds() {
    asm volatile("s_waitcnt lgkmcnt(0)" ::: "memory");
    __builtin_amdgcn_s_barrier();
    asm volatile("" ::: "memory");
}

// ---------------- prep: f32 -> bf16 for BOTH x and W_map in ONE launch ----------------
// (R7/R8 accounting: each extra launch costs ~20us wall + kernel time; the two
// conversions are independent elementwise ops -> one kernel, two block ranges.)
#define XN4  (BATCH * T_SEQ * INPUT / 4)        // 8388608 f32x4 groups
#define WN4  (16384 * HID / 4)                  // 524288
#define XBLK ((XN4 + 255) / 256)                // 32768 blocks for x
__global__ __launch_bounds__(256) void cvt_all_kernel(
    const float* __restrict__ x, short* __restrict__ x_bf,
    const float* __restrict__ wm, short* __restrict__ wm_bf) {
    const int b = blockIdx.x;
    const float* in; short* out; int i, n4;
    if (b < XBLK) { in = x;  out = x_bf;  i = b * 256 + threadIdx.x;          n4 = XN4; }
    else          { in = wm; out = wm_bf; i = (b - XBLK) * 256 + threadIdx.x; n4 = WN4; }
    if (i >= n4) return;
    f32x4 v = ((const f32x4*)in)[i];
    s16x4 o;
    #pragma unroll
    for (int j = 0; j < 4; ++j) o[j] = f2bf(v[j]);
    ((s16x4*)out)[i] = o;
}

// ---------------- Stage 1: recurrence (exact R2 structure, measured 449.8us) ----------------
// 32 blocks x 512 threads. Block: 16 batches.
// TRANSPOSED MFMA: C^T = W * h^T; C^T lane holds 4 consecutive hidden rows ->
// cvt_pk + single ds_write_b64. Group A (waves 0-3) owns even t, group B
// (waves 4-7) odd t; the non-owning group runs gate/agg/accx shadow work.
// 1 barrier/step. x prestaged bf16 (f32-direct poisons: R5 +122cyc, R8 +527cyc
// per step - conservative vmcnt(0) in shadow waits on just-issued loads).
// Tweak A (independent-MFMA tree) was null (R7) - chained form kept.
template<bool PRE>
__global__ __launch_bounds__(512, 2) void rnn_kernel(
    const float* __restrict__ xf_, const short* __restrict__ xb,
    const float* __restrict__ W_ih, const float* __restrict__ b_ih,
    const float* __restrict__ W_hh, const float* __restrict__ b_hh,
    const float* __restrict__ W_gate, const float* __restrict__ b_gate,
    float* __restrict__ agg_out)
{
    __shared__ __align__(16) short sh[2][16][136];

    const int tid  = threadIdx.x;
    const int wave = tid >> 6, lane = tid & 63;
    const int q = lane >> 4, l15 = lane & 15;
    const int b0 = blockIdx.x * 16;
    const int group = wave >> 2;          // 0: even steps, 1: odd steps
    const int gw = wave & 3;              // hidden rows [32*gw, 32*gw+32)
    const int R0 = 32 * gw, R1 = R0 + 16;

    // ---- one-time: weight A-frags (lane: W[row = Rt + l15][k = 32f + q*8 + j]) ----
    bf16x8 wih[2][2], whh[2][4], wgf[2][4];
    #pragma unroll
    for (int tile = 0; tile < 2; ++tile) {
        const int row = (tile ? R1 : R0) + l15;
        #pragma unroll
        for (int f = 0; f < 2; ++f) {
            const float* p = W_ih + row * INPUT + f * 32 + q * 8;
            bf16x8 v;
            #pragma unroll
            for (int j = 0; j < 8; ++j) v[j] = f2bf(p[j]);
            wih[tile][f] = v;
        }
        #pragma unroll
        for (int f = 0; f < 4; ++f) {
            const float* p = W_hh + row * HID + f * 32 + q * 8;
            bf16x8 v;
            #pragma unroll
            for (int j = 0; j < 8; ++j) v[j] = f2bf(p[j]);
            whh[tile][f] = v;
        }
        #pragma unroll
        for (int f = 0; f < 4; ++f) {
            const float* p = W_gate + row * HID + f * 32 + q * 8;
            bf16x8 v;
            #pragma unroll
            for (int j = 0; j < 8; ++j) v[j] = f2bf(p[j]);
            wgf[tile][f] = v;
        }
    }

    // ---- biases in C^T layout: row = Rt + q*4 + r ----
    f32x4 bias1[2], biasg[2], zero4;
    #pragma unroll
    for (int tile = 0; tile < 2; ++tile) {
        const int rbase = (tile ? R1 : R0) + q * 4;
        #pragma unroll
        for (int r = 0; r < 4; ++r) {
            bias1[tile][r] = b_ih[rbase + r] + b_hh[rbase + r];
            biasg[tile][r] = b_gate[rbase + r];
        }
    }
    #pragma unroll
    for (int r = 0; r < 4; ++r) zero4[r] = 0.0f;

    f32x4 agg0 = zero4, agg1 = zero4;
    f32x4 hpA = zero4, hpB = zero4;       // own h(s) values (f32, C^T layout)
    f32x4 accx0, accx1;                   // x-part for next own step
    bf16x8 xf0, xf1;                      // x B-frags for next own step

    const long lanebase = ((long)(b0 + l15) * T_SEQ) * INPUT + q * 8;
    const short* xb_lane = PRE ? (xb + lanebase) : nullptr;
    const float* xf_lane = PRE ? nullptr : (xf_ + lanebase);

    auto load_x = [&](int tt) {
        if constexpr (PRE) {
            const short* p = xb_lane + (long)tt * INPUT;
            xf0 = *(const bf16x8*)p;
            xf1 = *(const bf16x8*)(p + 32);
        } else {
            const float* p = xf_lane + (long)tt * INPUT;
            f32x4 a0 = *(const f32x4*)p,        a1 = *(const f32x4*)(p + 4);
            f32x4 a2 = *(const f32x4*)(p + 32), a3 = *(const f32x4*)(p + 36);
            #pragma unroll
            for (int j = 0; j < 4; ++j) {
                xf0[j] = f2bf(a0[j]); xf0[4 + j] = f2bf(a1[j]);
                xf1[j] = f2bf(a2[j]); xf1[4 + j] = f2bf(a3[j]);
            }
        }
    };

    // critical interval t: h(t) = tanh(W_hh h(t-1) + accx(t)); write buf[t&1]; prefetch x(t+2)
    auto critical = [&](int t) {
        const int rb = (t & 1) ^ 1, wb = t & 1;
        bf16x8 hf0 = *(const bf16x8*)&sh[rb][l15][q * 8];
        bf16x8 hf1 = *(const bf16x8*)&sh[rb][l15][32 + q * 8];
        bf16x8 hf2 = *(const bf16x8*)&sh[rb][l15][64 + q * 8];
        bf16x8 hf3 = *(const bf16x8*)&sh[rb][l15][96 + q * 8];
        f32x4 a0 = MFMA(whh[0][0], hf0, accx0, 0, 0, 0);
        f32x4 c0 = MFMA(whh[0][2], hf2, zero4, 0, 0, 0);
        f32x4 a1 = MFMA(whh[1][0], hf0, accx1, 0, 0, 0);
        f32x4 c1 = MFMA(whh[1][2], hf2, zero4, 0, 0, 0);
        a0 = MFMA(whh[0][1], hf1, a0, 0, 0, 0);
        c0 = MFMA(whh[0][3], hf3, c0, 0, 0, 0);
        a1 = MFMA(whh[1][1], hf1, a1, 0, 0, 0);
        c1 = MFMA(whh[1][3], hf3, c1, 0, 0, 0);
        // prefetch x(t+2) for next shadow's accx (fire & forget; clamped)
        int tt = t + 2; if (tt > T_SEQ - 1) tt = T_SEQ - 1;
        load_x(tt);
        hpA[0] = fast_tanh(a0[0] + c0[0]);
        hpA[1] = fast_tanh(a0[1] + c0[1]);
        hpA[2] = fast_tanh(a0[2] + c0[2]);
        hpA[3] = fast_tanh(a0[3] + c0[3]);
        hpB[0] = fast_tanh(a1[0] + c1[0]);
        hpB[1] = fast_tanh(a1[1] + c1[1]);
        hpB[2] = fast_tanh(a1[2] + c1[2]);
        hpB[3] = fast_tanh(a1[3] + c1[3]);
        u32x2 p0, p1;
        p0[0] = cvtpk_bf16(hpA[0], hpA[1]); p0[1] = cvtpk_bf16(hpA[2], hpA[3]);
        p1[0] = cvtpk_bf16(hpB[0], hpB[1]); p1[1] = cvtpk_bf16(hpB[2], hpB[3]);
        *(u32x2*)&sh[wb][l15][R0 + q * 4] = p0;
        *(u32x2*)&sh[wb][l15][R1 + q * 4] = p1;
    };

    // shadow interval t: gate(t-1) + agg, then accx(t+1) from prefetched xf
    auto shadow = [&](int t) {
        const int rb = (t & 1) ^ 1;
        bf16x8 gf0 = *(const bf16x8*)&sh[rb][l15][q * 8];
        bf16x8 gf1 = *(const bf16x8*)&sh[rb][l15][32 + q * 8];
        bf16x8 gf2 = *(const bf16x8*)&sh[rb][l15][64 + q * 8];
        bf16x8 gf3 = *(const bf16x8*)&sh[rb][l15][96 + q * 8];
        f32x4 g0 = MFMA(wgf[0][0], gf0, biasg[0], 0, 0, 0);
        f32x4 e0 = MFMA(wgf[0][2], gf2, zero4, 0, 0, 0);
        f32x4 g1 = MFMA(wgf[1][0], gf0, biasg[1], 0, 0, 0);
        f32x4 e1 = MFMA(wgf[1][2], gf2, zero4, 0, 0, 0);
        g0 = MFMA(wgf[0][1], gf1, g0, 0, 0, 0);
        e0 = MFMA(wgf[0][3], gf3, e0, 0, 0, 0);
        g1 = MFMA(wgf[1][1], gf1, g1, 0, 0, 0);
        e1 = MFMA(wgf[1][3], gf3, e1, 0, 0, 0);
        accx0 = MFMA(wih[0][0], xf0, bias1[0], 0, 0, 0);
        accx1 = MFMA(wih[1][0], xf0, bias1[1], 0, 0, 0);
        accx0 = MFMA(wih[0][1], xf1, accx0, 0, 0, 0);
        accx1 = MFMA(wih[1][1], xf1, accx1, 0, 0, 0);
        #pragma unroll
        for (int r = 0; r < 4; ++r) {
            agg0[r] += hpA[r] * hsig(g0[r] + e0[r]);
            agg1[r] += hpB[r] * hsig(g1[r] + e1[r]);
        }
    };

    // ---- prologue ----
    load_x(group);                         // x(0) for A, x(1) for B
    accx0 = MFMA(wih[0][0], xf0, bias1[0], 0, 0, 0);
    accx1 = MFMA(wih[1][0], xf0, bias1[1], 0, 0, 0);
    accx0 = MFMA(wih[0][1], xf1, accx0, 0, 0, 0);
    accx1 = MFMA(wih[1][1], xf1, accx1, 0, 0, 0);
    if (group == 0) {
        // h(0) = tanh(accx(0)); write buf[0]
        hpA[0] = fast_tanh(accx0[0]); hpA[1] = fast_tanh(accx0[1]);
        hpA[2] = fast_tanh(accx0[2]); hpA[3] = fast_tanh(accx0[3]);
        hpB[0] = fast_tanh(accx1[0]); hpB[1] = fast_tanh(accx1[1]);
        hpB[2] = fast_tanh(accx1[2]); hpB[3] = fast_tanh(accx1[3]);
        u32x2 p0, p1;
        p0[0] = cvtpk_bf16(hpA[0], hpA[1]); p0[1] = cvtpk_bf16(hpA[2], hpA[3]);
        p1[0] = cvtpk_bf16(hpB[0], hpB[1]); p1[1] = cvtpk_bf16(hpB[2], hpB[3]);
        *(u32x2*)&sh[0][l15][R0 + q * 4] = p0;
        *(u32x2*)&sh[0][l15][R1 + q * 4] = p1;
        load_x(2);                         // for shadow(1) -> accx(2)
    }
    wg_barrier_lds();

    // ---- main loop: t = 1 .. 1022 in pairs, tail t = 1023 ----
    if (group == 0) {
        for (int i = 0; i < 511; ++i) {
            shadow(2 * i + 1);   wg_barrier_lds();
            critical(2 * i + 2); wg_barrier_lds();
        }
        shadow(1023); wg_barrier_lds();
    } else {
        for (int i = 0; i < 511; ++i) {
            critical(2 * i + 1); wg_barrier_lds();
            shadow(2 * i + 2);   wg_barrier_lds();
        }
        critical(1023); wg_barrier_lds();
    }

    // ---- epilogue ----
    // B owns h(1023) (in sh[1]): compute its last gate term.
    if (group == 1) {
        bf16x8 gf0 = *(const bf16x8*)&sh[1][l15][q * 8];
        bf16x8 gf1 = *(const bf16x8*)&sh[1][l15][32 + q * 8];
        bf16x8 gf2 = *(const bf16x8*)&sh[1][l15][64 + q * 8];
        bf16x8 gf3 = *(const bf16x8*)&sh[1][l15][96 + q * 8];
        f32x4 g0 = MFMA(wgf[0][0], gf0, biasg[0], 0, 0, 0);
        f32x4 e0 = MFMA(wgf[0][2], gf2, zero4, 0, 0, 0);
        f32x4 g1 = MFMA(wgf[1][0], gf0, biasg[1], 0, 0, 0);
        f32x4 e1 = MFMA(wgf[1][2], gf2, zero4, 0, 0, 0);
        g0 = MFMA(wgf[0][1], gf1, g0, 0, 0, 0);
        e0 = MFMA(wgf[0][3], gf3, e0, 0, 0, 0);
        g1 = MFMA(wgf[1][1], gf1, g1, 0, 0, 0);
        e1 = MFMA(wgf[1][3], gf3, e1, 0, 0, 0);
        #pragma unroll
        for (int r = 0; r < 4; ++r) {
            agg0[r] += hpA[r] * hsig(g0[r] + e0[r]);
            agg1[r] += hpB[r] * hsig(g1[r] + e1[r]);
        }
    }
    wg_barrier_lds();                      // B's gf reads done before A overwrites LDS

    float* aggf = (float*)&sh[0][0][0];    // reuse as float[16][128]
    if (group == 0) {
        *(f32x4*)&aggf[l15 * HID + R0 + q * 4] = agg0;
        *(f32x4*)&aggf[l15 * HID + R1 + q * 4] = agg1;
    }
    wg_barrier_lds();
    if (group == 1) {
        const float s = 1.0f / (float)T_SEQ;
        f32x4 t0 = *(const f32x4*)&aggf[l15 * HID + R0 + q * 4];
        f32x4 t1 = *(const f32x4*)&aggf[l15 * HID + R1 + q * 4];
        #pragma unroll
        for (int r = 0; r < 4; ++r) { t0[r] = (t0[r] + agg0[r]) * s; t1[r] = (t1[r] + agg1[r]) * s; }
        *(f32x4*)&agg_out[(long)(b0 + l15) * HID + R0 + q * 4] = t0;
        *(f32x4*)&agg_out[(long)(b0 + l15) * HID + R1 + q * 4] = t1;
    }
}

// ---------------- Stage 2: mapped = agg @ W_map^T + b_map, FUSED pool+gate ----------------
// Block (mb, nb): batches mb*16..+16, cols nb*128..+128. The block covers exactly
// one pool-window row -> 4x4 pooling is block-local. shfl over 4-lane w-groups,
// per-wave LDS partials over h, gate = hsig(sum/16), multiply before the store.
template<bool PRE>
__global__ __launch_bounds__(256) void map_kernel(
    const float* __restrict__ agg, const float* __restrict__ Wf,
    const short* __restrict__ Wb, const float* __restrict__ b_map,
    float* __restrict__ out)
{
    __shared__ float sh_pool[4][16][8];
    __shared__ float sh_gate[16][8];

    const int tid  = threadIdx.x;
    const int wave = tid >> 6, lane = tid & 63;
    const int q = lane >> 4, l15 = lane & 15;
    const int mb = blockIdx.x & 31;
    const int nb = blockIdx.x >> 5;
    const int b0 = mb * 16;
    const int n0 = nb * 128 + wave * 32;

    bf16x8 af[4];
    #pragma unroll
    for (int kb = 0; kb < 4; ++kb) {
        const float* p = agg + (b0 + l15) * HID + kb * 32 + q * 8;
        bf16x8 f;
        #pragma unroll
        for (int j = 0; j < 8; ++j) f[j] = f2bf(p[j]);
        af[kb] = f;
    }
    f32x4 cc[2];
    #pragma unroll
    for (int tn = 0; tn < 2; ++tn) {
        int nn = n0 + tn * 16 + l15;
        float bias = b_map[nn];
        f32x4 c;
        #pragma unroll
        for (int r = 0; r < 4; ++r) c[r] = bias;
        #pragma unroll
        for (int kb = 0; kb < 4; ++kb) {
            bf16x8 f;
            if (PRE) {
                f = *(const bf16x8*)(Wb + (long)nn * HID + kb * 32 + q * 8);
            } else {
                const float* p = Wf + (long)nn * HID + kb * 32 + q * 8;
                #pragma unroll
                for (int j = 0; j < 8; ++j) f[j] = f2bf(p[j]);
            }
            c = __builtin_amdgcn_mfma_f32_16x16x32_bf16(af[kb], f, c, 0, 0, 0);
        }
        cc[tn] = c;
        // pool partial: sum over 4-lane w-groups
        f32x4 t = c;
        #pragma unroll
        for (int r = 0; r < 4; ++r) {
            t[r] += __shfl_xor(t[r], 1);
            t[r] += __shfl_xor(t[r], 2);
        }
        if ((l15 & 3) == 0) {
            int pw = tn * 4 + (l15 >> 2);
            #pragma unroll
            for (int r = 0; r < 4; ++r) sh_pool[wave][q * 4 + r][pw] = t[r];
        }
    }
    __syncthreads();
    if (tid < 128) {
        int b = tid >> 3, pw = tid & 7;
        float s = sh_pool[0][b][pw] + sh_pool[1][b][pw] +
                  sh_pool[2][b][pw] + sh_pool[3][b][pw];
        sh_gate[b][pw] = hsig(s * (1.0f / 16.0f));
    }
    __syncthreads();
    #pragma unroll
    for (int tn = 0; tn < 2; ++tn) {
        int nn = n0 + tn * 16 + l15;
        int pw = tn * 4 + (l15 >> 2);
        #pragma unroll
        for (int r = 0; r < 4; ++r)
            out[(long)(b0 + q * 4 + r) * 16384 + nn] = cc[tn][r] * sh_gate[q * 4 + r][pw];
    }
}

extern "C" void kernel_launch(void* const* d_in, const int* in_sizes, int n_in,
                              void* d_out, int out_size, void* d_ws, size_t ws_size,
                              hipStream_t stream) {
    const float* x      = (const float*)d_in[0];
    const float* W_ih   = (const float*)d_in[1];
    const float* b_ih   = (const float*)d_in[2];
    const float* W_hh   = (const float*)d_in[3];
    const float* b_hh   = (const float*)d_in[4];
    const float* W_gate = (const float*)d_in[5];
    const float* b_gate = (const float*)d_in[6];
    const float* W_map  = (const float*)d_in[7];
    const float* b_map  = (const float*)d_in[8];
    float* out = (float*)d_out;

    const size_t xb_bytes  = (size_t)BATCH * T_SEQ * INPUT * 2;
    const size_t wm_bytes  = (size_t)16384 * HID * 2;
    const size_t agg_bytes = (size_t)BATCH * HID * 4;
    const bool pre = ws_size >= xb_bytes + wm_bytes + agg_bytes;

    if (pre) {
        short* x_bf  = (short*)d_ws;
        short* wm_bf = (short*)((char*)d_ws + xb_bytes);
        float* agg   = (float*)((char*)d_ws + xb_bytes + wm_bytes);

        const int wblk = (WN4 + 255) / 256;
        cvt_all_kernel<<<XBLK + wblk, 256, 0, stream>>>(x, x_bf, W_map, wm_bf);
        rnn_kernel<true><<<32, 512, 0, stream>>>(x, x_bf, W_ih, b_ih, W_hh, b_hh,
                                                 W_gate, b_gate, agg);
        map_kernel<true><<<4096, 256, 0, stream>>>(agg, W_map, wm_bf, b_map, out);
    } else {
        float* agg = (float*)d_ws;
        rnn_kernel<false><<<32, 512, 0, stream>>>(x, nullptr, W_ih, b_ih, W_hh, b_hh,
                                                  W_gate, b_gate, agg);
        map_kernel<false><<<4096, 256, 0, stream>>>(agg, W_map, nullptr, b_map, out);
    }
}

// Round 10
// 650.799 us; speedup vs baseline: 1.3535x; 1.0521x over previous
//
#include <hip/hip_runtime.h>
#include <hip/hip_bf16.h>

#define T_SEQ 1024
#define BATCH 512
#define INPUT 64
#define HID   128

typedef __attribute__((ext_vector_type(8))) short bf16x8;
typedef __attribute__((ext_vector_type(4))) short s16x4;
typedef __attribute__((ext_vector_type(4))) float f32x4;
typedef __attribute__((ext_vector_type(2))) unsigned int u32x2;

#define MFMA __builtin_amdgcn_mfma_f32_16x16x32_bf16
#define WN4  (16384 * HID / 4)

__device__ __forceinline__ short f2bf(float f) {
    union { float f; unsigned u; } v; v.f = f;
    unsigned r = (v.u + 0x7FFFu + ((v.u >> 16) & 1u)) >> 16;
    return (short)r;
}

// packed RNE f32x2 -> bf16x2
__device__ __forceinline__ unsigned cvtpk_bf16(float lo, float hi) {
    unsigned r;
    asm("v_cvt_pk_bf16_f32 %0, %1, %2" : "=v"(r) : "v"(lo), "v"(hi));
    return r;
}

// 8 f32 -> bf16x8 via 4 cvt_pk
__device__ __forceinline__ bf16x8 pack8(f32x4 a, f32x4 b) {
    union { unsigned u[4]; bf16x8 v; } r;
    r.u[0] = cvtpk_bf16(a[0], a[1]);
    r.u[1] = cvtpk_bf16(a[2], a[3]);
    r.u[2] = cvtpk_bf16(b[0], b[1]);
    r.u[3] = cvtpk_bf16(b[2], b[3]);
    return r.v;
}

// tanh(x) = 1 - 2/(exp(2x)+1); inf-safe
__device__ __forceinline__ float fast_tanh(float s) {
    float e = __expf(2.0f * s);
    return 1.0f - 2.0f * __builtin_amdgcn_rcpf(e + 1.0f);
}

__device__ __forceinline__ float hsig(float v) {
    return __builtin_amdgcn_fmed3f(v * 0.16666666666666666f + 0.5f, 0.0f, 1.0f);
}

// Barrier draining ONLY lgkmcnt (LDS). Global loads stay in flight.
__device__ __forceinline__ void wg_barrier_lds() {
    asm volatile("s_waitcnt lgkmcnt(0)" ::: "memory");
    __builtin_amdgcn_s_barrier();
    asm volatile("" ::: "memory");
}

// ---------------- Stage 1: recurrence + in-kernel x loader + fused W_map cvt --------
// Grid 40 x 640. Blocks 0-31: recurrence, 16 batches each, 10 waves:
//   waves 0-7 = R2 consumer structure (group A even t / group B odd t, 1 barrier/step);
//   waves 8-9 = LOADER: stream-convert this block's x (f32->bf16) into an 8-slot
//   LDS ring, 7 steps ahead. Their vmcnt stalls are decoupled from the critical
//   chain (R5/R8 failures were CONSUMER waves touching raw-f32 regs). The per-step
//   lgkm barrier orders ring writes->reads for free. Kills the cvt_x kernel (~40us).
// Blocks 32-39: W_map f32->bf16 grid-stride (R8-proven safe; no barriers).
// Barrier count (must match): consumers B0 + B1 + 1023 + 2 = 1027;
//   loaders 2 + 4*254 + (7 idle + 2 epi) = 1027.
// Ring schedule: prologue fills slots 0..7 (= x(0..7)); loop interval t (1..1016)
//   writes x(t+7) -> slot (t+7)&7 from a 4-deep named-reg pipeline (reissue x(t+11));
//   shadow(t) reads slot (t+1)&7; write at t+7's slot is >=2 barriers after its
//   last reader (x(t-1) read at interval t-2). Tail reads (t>1016) hit stale
//   slots but feed only discarded accx values (finite).
__global__ __launch_bounds__(640, 2) void rnn_kernel(
    const float* __restrict__ xf_,
    const float* __restrict__ W_ih, const float* __restrict__ b_ih,
    const float* __restrict__ W_hh, const float* __restrict__ b_hh,
    const float* __restrict__ W_gate, const float* __restrict__ b_gate,
    float* __restrict__ agg_out,
    const float* __restrict__ W_map, short* __restrict__ wm_bf)
{
    if (blockIdx.x >= 32) {
        // ---- W_map f32 -> bf16, grid-stride over 8 blocks ----
        for (int i = (blockIdx.x - 32) * 640 + threadIdx.x; i < WN4; i += 8 * 640) {
            f32x4 v = ((const f32x4*)W_map)[i];
            s16x4 o;
            #pragma unroll
            for (int j = 0; j < 4; ++j) o[j] = f2bf(v[j]);
            ((s16x4*)wm_bf)[i] = o;
        }
        return;
    }

    __shared__ __align__(16) short sh[2][16][136];   // h exchange (pitch 136: 4-bank row stride)
    __shared__ __align__(16) short sh_x[8][16][72];  // x ring     (pitch  72: same 4-bank stride)

    const int tid  = threadIdx.x;
    const int wave = tid >> 6, lane = tid & 63;
    const int b0 = blockIdx.x * 16;

    if (wave >= 8) {
        // ================= LOADER waves (8,9) =================
        const int bi = (wave - 8) * 8 + (lane >> 3);     // batch row 0..15
        const int i8 = (lane & 7) * 8;                   // input offset (8 f32 = 32B contiguous)
        const float* xp = xf_ + ((long)(b0 + bi) * T_SEQ) * INPUT + i8;

        // prologue: fill slots 0..7 with x(0..7)
        for (int s = 0; s < 8; s += 2) {
            f32x4 a0 = *(const f32x4*)(xp + (long)s * INPUT);
            f32x4 a1 = *(const f32x4*)(xp + (long)s * INPUT + 4);
            f32x4 c0 = *(const f32x4*)(xp + (long)(s + 1) * INPUT);
            f32x4 c1 = *(const f32x4*)(xp + (long)(s + 1) * INPUT + 4);
            *(bf16x8*)&sh_x[s][bi][i8]     = pack8(a0, a1);
            *(bf16x8*)&sh_x[s + 1][bi][i8] = pack8(c0, c1);
        }
        // 4-deep reg pipeline (named regs - no runtime-indexed arrays):
        // p1=x(8), p2=x(9), p3=x(10), p0=x(11)
        f32x4 p1a = *(const f32x4*)(xp + 8L * INPUT),  p1b = *(const f32x4*)(xp + 8L * INPUT + 4);
        f32x4 p2a = *(const f32x4*)(xp + 9L * INPUT),  p2b = *(const f32x4*)(xp + 9L * INPUT + 4);
        f32x4 p3a = *(const f32x4*)(xp + 10L * INPUT), p3b = *(const f32x4*)(xp + 10L * INPUT + 4);
        f32x4 p0a = *(const f32x4*)(xp + 11L * INPUT), p0b = *(const f32x4*)(xp + 11L * INPUT + 4);

        wg_barrier_lds();   // B0
        wg_barrier_lds();   // B1
        for (int i = 0; i < 254; ++i) {
            const int t4 = 4 * i;
            long tt;
            // interval t4+1: write x(t4+8) -> slot (t4+8)&7 ; reissue x(t4+12)
            *(bf16x8*)&sh_x[(t4 + 8) & 7][bi][i8] = pack8(p1a, p1b);
            tt = (t4 + 12 > 1023) ? 1023 : (t4 + 12);
            p1a = *(const f32x4*)(xp + tt * INPUT); p1b = *(const f32x4*)(xp + tt * INPUT + 4);
            wg_barrier_lds();
            // interval t4+2
            *(bf16x8*)&sh_x[(t4 + 9) & 7][bi][i8] = pack8(p2a, p2b);
            tt = (t4 + 13 > 1023) ? 1023 : (t4 + 13);
            p2a = *(const f32x4*)(xp + tt * INPUT); p2b = *(const f32x4*)(xp + tt * INPUT + 4);
            wg_barrier_lds();
            // interval t4+3
            *(bf16x8*)&sh_x[(t4 + 10) & 7][bi][i8] = pack8(p3a, p3b);
            tt = (t4 + 14 > 1023) ? 1023 : (t4 + 14);
            p3a = *(const f32x4*)(xp + tt * INPUT); p3b = *(const f32x4*)(xp + tt * INPUT + 4);
            wg_barrier_lds();
            // interval t4+4
            *(bf16x8*)&sh_x[(t4 + 11) & 7][bi][i8] = pack8(p0a, p0b);
            tt = (t4 + 15 > 1023) ? 1023 : (t4 + 15);
            p0a = *(const f32x4*)(xp + tt * INPUT); p0b = *(const f32x4*)(xp + tt * INPUT + 4);
            wg_barrier_lds();
        }
        // intervals 1017..1023 idle + 2 epilogue barriers
        for (int k = 0; k < 9; ++k) wg_barrier_lds();
        return;
    }

    // ================= CONSUMER waves (0-7) =================
    const int q = lane >> 4, l15 = lane & 15;
    const int group = wave >> 2;          // 0: even steps, 1: odd steps
    const int gw = wave & 3;              // hidden rows [32*gw, 32*gw+32)
    const int R0 = 32 * gw, R1 = R0 + 16;

    // ---- one-time: weight A-frags (lane: W[row = Rt + l15][k = 32f + q*8 + j]) ----
    bf16x8 wih[2][2], whh[2][4], wgf[2][4];
    #pragma unroll
    for (int tile = 0; tile < 2; ++tile) {
        const int row = (tile ? R1 : R0) + l15;
        #pragma unroll
        for (int f = 0; f < 2; ++f) {
            const float* p = W_ih + row * INPUT + f * 32 + q * 8;
            bf16x8 v;
            #pragma unroll
            for (int j = 0; j < 8; ++j) v[j] = f2bf(p[j]);
            wih[tile][f] = v;
        }
        #pragma unroll
        for (int f = 0; f < 4; ++f) {
            const float* p = W_hh + row * HID + f * 32 + q * 8;
            bf16x8 v;
            #pragma unroll
            for (int j = 0; j < 8; ++j) v[j] = f2bf(p[j]);
            whh[tile][f] = v;
        }
        #pragma unroll
        for (int f = 0; f < 4; ++f) {
            const float* p = W_gate + row * HID + f * 32 + q * 8;
            bf16x8 v;
            #pragma unroll
            for (int j = 0; j < 8; ++j) v[j] = f2bf(p[j]);
            wgf[tile][f] = v;
        }
    }

    // ---- biases in C^T layout: row = Rt + q*4 + r ----
    f32x4 bias1[2], biasg[2], zero4;
    #pragma unroll
    for (int tile = 0; tile < 2; ++tile) {
        const int rbase = (tile ? R1 : R0) + q * 4;
        #pragma unroll
        for (int r = 0; r < 4; ++r) {
            bias1[tile][r] = b_ih[rbase + r] + b_hh[rbase + r];
            biasg[tile][r] = b_gate[rbase + r];
        }
    }
    #pragma unroll
    for (int r = 0; r < 4; ++r) zero4[r] = 0.0f;

    f32x4 agg0 = zero4, agg1 = zero4;
    f32x4 hpA = zero4, hpB = zero4;       // own h(s) values (f32, C^T layout)
    f32x4 accx0, accx1;                   // x-part for next own step

    // critical t: h(t) = tanh(W_hh h(t-1) + accx(t)); write sh[t&1]
    auto critical = [&](int t) {
        const int rb = (t & 1) ^ 1, wb = t & 1;
        bf16x8 hf0 = *(const bf16x8*)&sh[rb][l15][q * 8];
        bf16x8 hf1 = *(const bf16x8*)&sh[rb][l15][32 + q * 8];
        bf16x8 hf2 = *(const bf16x8*)&sh[rb][l15][64 + q * 8];
        bf16x8 hf3 = *(const bf16x8*)&sh[rb][l15][96 + q * 8];
        f32x4 a0 = MFMA(whh[0][0], hf0, accx0, 0, 0, 0);
        f32x4 c0 = MFMA(whh[0][2], hf2, zero4, 0, 0, 0);
        f32x4 a1 = MFMA(whh[1][0], hf0, accx1, 0, 0, 0);
        f32x4 c1 = MFMA(whh[1][2], hf2, zero4, 0, 0, 0);
        a0 = MFMA(whh[0][1], hf1, a0, 0, 0, 0);
        c0 = MFMA(whh[0][3], hf3, c0, 0, 0, 0);
        a1 = MFMA(whh[1][1], hf1, a1, 0, 0, 0);
        c1 = MFMA(whh[1][3], hf3, c1, 0, 0, 0);
        hpA[0] = fast_tanh(a0[0] + c0[0]);
        hpA[1] = fast_tanh(a0[1] + c0[1]);
        hpA[2] = fast_tanh(a0[2] + c0[2]);
        hpA[3] = fast_tanh(a0[3] + c0[3]);
        hpB[0] = fast_tanh(a1[0] + c1[0]);
        hpB[1] = fast_tanh(a1[1] + c1[1]);
        hpB[2] = fast_tanh(a1[2] + c1[2]);
        hpB[3] = fast_tanh(a1[3] + c1[3]);
        u32x2 p0, p1;
        p0[0] = cvtpk_bf16(hpA[0], hpA[1]); p0[1] = cvtpk_bf16(hpA[2], hpA[3]);
        p1[0] = cvtpk_bf16(hpB[0], hpB[1]); p1[1] = cvtpk_bf16(hpB[2], hpB[3]);
        *(u32x2*)&sh[wb][l15][R0 + q * 4] = p0;
        *(u32x2*)&sh[wb][l15][R1 + q * 4] = p1;
    };

    // shadow t: gate(t-1) + agg; accx(t+1) from x ring slot (t+1)&7
    auto shadow = [&](int t) {
        const int rb = (t & 1) ^ 1;
        const int xs = (t + 1) & 7;
        bf16x8 gf0 = *(const bf16x8*)&sh[rb][l15][q * 8];
        bf16x8 gf1 = *(const bf16x8*)&sh[rb][l15][32 + q * 8];
        bf16x8 gf2 = *(const bf16x8*)&sh[rb][l15][64 + q * 8];
        bf16x8 gf3 = *(const bf16x8*)&sh[rb][l15][96 + q * 8];
        bf16x8 xf0 = *(const bf16x8*)&sh_x[xs][l15][q * 8];
        bf16x8 xf1 = *(const bf16x8*)&sh_x[xs][l15][32 + q * 8];
        f32x4 g0 = MFMA(wgf[0][0], gf0, biasg[0], 0, 0, 0);
        f32x4 e0 = MFMA(wgf[0][2], gf2, zero4, 0, 0, 0);
        f32x4 g1 = MFMA(wgf[1][0], gf0, biasg[1], 0, 0, 0);
        f32x4 e1 = MFMA(wgf[1][2], gf2, zero4, 0, 0, 0);
        g0 = MFMA(wgf[0][1], gf1, g0, 0, 0, 0);
        e0 = MFMA(wgf[0][3], gf3, e0, 0, 0, 0);
        g1 = MFMA(wgf[1][1], gf1, g1, 0, 0, 0);
        e1 = MFMA(wgf[1][3], gf3, e1, 0, 0, 0);
        accx0 = MFMA(wih[0][0], xf0, bias1[0], 0, 0, 0);
        accx1 = MFMA(wih[1][0], xf0, bias1[1], 0, 0, 0);
        accx0 = MFMA(wih[0][1], xf1, accx0, 0, 0, 0);
        accx1 = MFMA(wih[1][1], xf1, accx1, 0, 0, 0);
        #pragma unroll
        for (int r = 0; r < 4; ++r) {
            agg0[r] += hpA[r] * hsig(g0[r] + e0[r]);
            agg1[r] += hpB[r] * hsig(g1[r] + e1[r]);
        }
    };

    wg_barrier_lds();                      // B0: x ring slots 0..7 ready

    // ---- prologue: accx(group) from ring; A also computes h(0) ----
    {
        bf16x8 xa0 = *(const bf16x8*)&sh_x[group][l15][q * 8];
        bf16x8 xa1 = *(const bf16x8*)&sh_x[group][l15][32 + q * 8];
        accx0 = MFMA(wih[0][0], xa0, bias1[0], 0, 0, 0);
        accx1 = MFMA(wih[1][0], xa0, bias1[1], 0, 0, 0);
        accx0 = MFMA(wih[0][1], xa1, accx0, 0, 0, 0);
        accx1 = MFMA(wih[1][1], xa1, accx1, 0, 0, 0);
    }
    if (group == 0) {
        hpA[0] = fast_tanh(accx0[0]); hpA[1] = fast_tanh(accx0[1]);
        hpA[2] = fast_tanh(accx0[2]); hpA[3] = fast_tanh(accx0[3]);
        hpB[0] = fast_tanh(accx1[0]); hpB[1] = fast_tanh(accx1[1]);
        hpB[2] = fast_tanh(accx1[2]); hpB[3] = fast_tanh(accx1[3]);
        u32x2 p0, p1;
        p0[0] = cvtpk_bf16(hpA[0], hpA[1]); p0[1] = cvtpk_bf16(hpA[2], hpA[3]);
        p1[0] = cvtpk_bf16(hpB[0], hpB[1]); p1[1] = cvtpk_bf16(hpB[2], hpB[3]);
        *(u32x2*)&sh[0][l15][R0 + q * 4] = p0;
        *(u32x2*)&sh[0][l15][R1 + q * 4] = p1;
    }
    wg_barrier_lds();                      // B1

    // ---- main loop: t = 1 .. 1022 in pairs, tail t = 1023 ----
    if (group == 0) {
        for (int i = 0; i < 511; ++i) {
            shadow(2 * i + 1);   wg_barrier_lds();
            critical(2 * i + 2); wg_barrier_lds();
        }
        shadow(1023); wg_barrier_lds();
    } else {
        for (int i = 0; i < 511; ++i) {
            critical(2 * i + 1); wg_barrier_lds();
            shadow(2 * i + 2);   wg_barrier_lds();
        }
        critical(1023); wg_barrier_lds();
    }

    // ---- epilogue ----
    if (group == 1) {
        bf16x8 gf0 = *(const bf16x8*)&sh[1][l15][q * 8];
        bf16x8 gf1 = *(const bf16x8*)&sh[1][l15][32 + q * 8];
        bf16x8 gf2 = *(const bf16x8*)&sh[1][l15][64 + q * 8];
        bf16x8 gf3 = *(const bf16x8*)&sh[1][l15][96 + q * 8];
        f32x4 g0 = MFMA(wgf[0][0], gf0, biasg[0], 0, 0, 0);
        f32x4 e0 = MFMA(wgf[0][2], gf2, zero4, 0, 0, 0);
        f32x4 g1 = MFMA(wgf[1][0], gf0, biasg[1], 0, 0, 0);
        f32x4 e1 = MFMA(wgf[1][2], gf2, zero4, 0, 0, 0);
        g0 = MFMA(wgf[0][1], gf1, g0, 0, 0, 0);
        e0 = MFMA(wgf[0][3], gf3, e0, 0, 0, 0);
        g1 = MFMA(wgf[1][1], gf1, g1, 0, 0, 0);
        e1 = MFMA(wgf[1][3], gf3, e1, 0, 0, 0);
        #pragma unroll
        for (int r = 0; r < 4; ++r) {
            agg0[r] += hpA[r] * hsig(g0[r] + e0[r]);
            agg1[r] += hpB[r] * hsig(g1[r] + e1[r]);
        }
    }
    wg_barrier_lds();                      // B's gf reads done before A overwrites LDS

    float* aggf = (float*)&sh[0][0][0];    // reuse as float[16][128]
    if (group == 0) {
        *(f32x4*)&aggf[l15 * HID + R0 + q * 4] = agg0;
        *(f32x4*)&aggf[l15 * HID + R1 + q * 4] = agg1;
    }
    wg_barrier_lds();
    if (group == 1) {
        const float s = 1.0f / (float)T_SEQ;
        f32x4 t0 = *(const f32x4*)&aggf[l15 * HID + R0 + q * 4];
        f32x4 t1 = *(const f32x4*)&aggf[l15 * HID + R1 + q * 4];
        #pragma unroll
        for (int r = 0; r < 4; ++r) { t0[r] = (t0[r] + agg0[r]) * s; t1[r] = (t1[r] + agg1[r]) * s; }
        *(f32x4*)&agg_out[(long)(b0 + l15) * HID + R0 + q * 4] = t0;
        *(f32x4*)&agg_out[(long)(b0 + l15) * HID + R1 + q * 4] = t1;
    }
}

// ---------------- Stage 2: mapped = agg @ W_map^T + b_map, FUSED pool+gate ----------------
// Block (mb, nb): batches mb*16..+16, cols nb*128..+128. The block covers exactly
// one pool-window row -> 4x4 pooling is block-local. shfl over 4-lane w-groups,
// per-wave LDS partials over h, gate = hsig(sum/16), multiply before the store.
template<bool PRE>
__global__ __launch_bounds__(256) void map_kernel(
    const float* __restrict__ agg, const float* __restrict__ Wf,
    const short* __restrict__ Wb, const float* __restrict__ b_map,
    float* __restrict__ out)
{
    __shared__ float sh_pool[4][16][8];
    __shared__ float sh_gate[16][8];

    const int tid  = threadIdx.x;
    const int wave = tid >> 6, lane = tid & 63;
    const int q = lane >> 4, l15 = lane & 15;
    const int mb = blockIdx.x & 31;
    const int nb = blockIdx.x >> 5;
    const int b0 = mb * 16;
    const int n0 = nb * 128 + wave * 32;

    bf16x8 af[4];
    #pragma unroll
    for (int kb = 0; kb < 4; ++kb) {
        const float* p = agg + (b0 + l15) * HID + kb * 32 + q * 8;
        bf16x8 f;
        #pragma unroll
        for (int j = 0; j < 8; ++j) f[j] = f2bf(p[j]);
        af[kb] = f;
    }
    f32x4 cc[2];
    #pragma unroll
    for (int tn = 0; tn < 2; ++tn) {
        int nn = n0 + tn * 16 + l15;
        float bias = b_map[nn];
        f32x4 c;
        #pragma unroll
        for (int r = 0; r < 4; ++r) c[r] = bias;
        #pragma unroll
        for (int kb = 0; kb < 4; ++kb) {
            bf16x8 f;
            if (PRE) {
                f = *(const bf16x8*)(Wb + (long)nn * HID + kb * 32 + q * 8);
            } else {
                const float* p = Wf + (long)nn * HID + kb * 32 + q * 8;
                #pragma unroll
                for (int j = 0; j < 8; ++j) f[j] = f2bf(p[j]);
            }
            c = __builtin_amdgcn_mfma_f32_16x16x32_bf16(af[kb], f, c, 0, 0, 0);
        }
        cc[tn] = c;
        // pool partial: sum over 4-lane w-groups
        f32x4 t = c;
        #pragma unroll
        for (int r = 0; r < 4; ++r) {
            t[r] += __shfl_xor(t[r], 1);
            t[r] += __shfl_xor(t[r], 2);
        }
        if ((l15 & 3) == 0) {
            int pw = tn * 4 + (l15 >> 2);
            #pragma unroll
            for (int r = 0; r < 4; ++r) sh_pool[wave][q * 4 + r][pw] = t[r];
        }
    }
    __syncthreads();
    if (tid < 128) {
        int b = tid >> 3, pw = tid & 7;
        float s = sh_pool[0][b][pw] + sh_pool[1][b][pw] +
                  sh_pool[2][b][pw] + sh_pool[3][b][pw];
        sh_gate[b][pw] = hsig(s * (1.0f / 16.0f));
    }
    __syncthreads();
    #pragma unroll
    for (int tn = 0; tn < 2; ++tn) {
        int nn = n0 + tn * 16 + l15;
        int pw = tn * 4 + (l15 >> 2);
        #pragma unroll
        for (int r = 0; r < 4; ++r)
            out[(long)(b0 + q * 4 + r) * 16384 + nn] = cc[tn][r] * sh_gate[q * 4 + r][pw];
    }
}

extern "C" void kernel_launch(void* const* d_in, const int* in_sizes, int n_in,
                              void* d_out, int out_size, void* d_ws, size_t ws_size,
                              hipStream_t stream) {
    const float* x      = (const float*)d_in[0];
    const float* W_ih   = (const float*)d_in[1];
    const float* b_ih   = (const float*)d_in[2];
    const float* W_hh   = (const float*)d_in[3];
    const float* b_hh   = (const float*)d_in[4];
    const float* W_gate = (const float*)d_in[5];
    const float* b_gate = (const float*)d_in[6];
    const float* W_map  = (const float*)d_in[7];
    const float* b_map  = (const float*)d_in[8];
    float* out = (float*)d_out;

    const size_t wm_bytes  = (size_t)16384 * HID * 2;
    const size_t agg_bytes = (size_t)BATCH * HID * 4;
    const bool pre = ws_size >= wm_bytes + agg_bytes;

    if (pre) {
        short* wm_bf = (short*)d_ws;
        float* agg   = (float*)((char*)d_ws + wm_bytes);

        // blocks 0-31: recurrence (with loader waves); 32-39: W_map cvt
        rnn_kernel<<<40, 640, 0, stream>>>(x, W_ih, b_ih, W_hh, b_hh,
                                           W_gate, b_gate, agg, W_map, wm_bf);
        map_kernel<true><<<4096, 256, 0, stream>>>(agg, W_map, wm_bf, b_map, out);
    } else {
        float* agg = (float*)d_ws;
        rnn_kernel<<<32, 640, 0, stream>>>(x, W_ih, b_ih, W_hh, b_hh,
                                           W_gate, b_gate, agg, nullptr, nullptr);
        map_kernel<false><<<4096, 256, 0, stream>>>(agg, W_map, nullptr, b_map, out);
    }
}